// Round 12
// baseline (237.864 us; speedup 1.0000x reference)
//
#include <hip/hip_runtime.h>
#include <hip/hip_bf16.h>

// Problem constants
static constexpr int NB = 16;     // batches
static constexpr int NP = 2048;   // points per batch
static constexpr int NC = 128;    // channels
#define ALPHA_F ((float)(8.0/9.0))
#define OMA_F   ((float)(1.0 - 8.0/9.0))

typedef __attribute__((ext_vector_type(8))) short bfrag;   // 8 bf16 (4 VGPR)
typedef __attribute__((ext_vector_type(4))) float ffrag;   // 4 fp32 acc

union BU { bfrag v; uint4 u; unsigned int w[4]; };

// split two floats into packed bf16 hi pair + bf16 lo pair
__device__ inline void split2(float x, float y, unsigned& hi, unsigned& lo) {
    __hip_bfloat162 h = __float22bfloat162_rn(make_float2(x, y));
    float2 hb = __bfloat1622float2(h);
    __hip_bfloat162 l = __float22bfloat162_rn(make_float2(x - hb.x, y - hb.y));
    __builtin_memcpy(&hi, &h, 4);
    __builtin_memcpy(&lo, &l, 4);
}

__device__ inline void split1(float x, unsigned short& h, unsigned short& l) {
    __hip_bfloat16 hb = __float2bfloat16(x);
    float hf = __bfloat162float(hb);
    __hip_bfloat16 lb = __float2bfloat16(x - hf);
    __builtin_memcpy(&h, &hb, 2);
    __builtin_memcpy(&l, &lb, 2);
}

// ---------------------------------------------------------------------------
// Combined prep (one-time):
//  blocks [0,64):   pre-split W into MFMA-frag-ordered bf16 hi/lo uint4 pairs
//  blocks [64,192): pack candidates cand[b][j] = {x, y, z, |p|^2}
// ---------------------------------------------------------------------------
__global__ __launch_bounds__(256) void prep_kernel(const float* __restrict__ Wc,
                                                   const float* __restrict__ Wg,
                                                   const float* __restrict__ xyz,
                                                   uint4* __restrict__ WP,
                                                   float4* __restrict__ cand) {
    if (blockIdx.x < 64) {
        int t = blockIdx.x * 256 + threadIdx.x;
        int ncol = t & 127;
        int quad = (t >> 7) & 3;
        int s = (t >> 9) & 3;
        int mat = (t >> 11) & 1;
        int layer = t >> 12;
        const float* W = (mat ? Wg : Wc) + (size_t)layer * NC * NC + (size_t)ncol * NC + s * 32 + quad * 8;
        float4 a = *((const float4*)W);
        float4 b = *((const float4*)(W + 4));
        BU hi, lo;
        split2(a.x, a.y, hi.w[0], lo.w[0]);
        split2(a.z, a.w, hi.w[1], lo.w[1]);
        split2(b.x, b.y, hi.w[2], lo.w[2]);
        split2(b.z, b.w, hi.w[3], lo.w[3]);
        WP[t * 2] = hi.u;
        WP[t * 2 + 1] = lo.u;
    } else {
        int idx = (blockIdx.x - 64) * 256 + threadIdx.x;   // 0..32767
        int b = idx >> 11, m = idx & 2047;
        const float* X = xyz + (size_t)b * 3 * NP;
        float x = X[m], y = X[NP + m], z = X[2 * NP + m];
        cand[idx] = make_float4(x, y, z, x * x + y * y + z * z);
    }
}

// ---------------------------------------------------------------------------
// KNN v5: wave-uniform candidate scan via the scalar pipe.
// Block = 256 thr = 4 waves; wave w owns candidate stripe [512w, 512w+512)
// for ALL 64 points of the tile (one point per lane). Candidate addresses are
// wave-uniform (readfirstlane-pinned stripe base) -> fetched once per wave
// (s_load / broadcast), ZERO LDS in the main loop.
// Pass 1: per-8-candidate group min + branchless top-8-of-64 groups.
// Pass 2: full (d,j) insert over the 8 winning groups (global reads, L1-hot).
// Merge across the 4 stripes via 17 KB LDS scratch (proven v3 network).
// Contiguous stripes + stable merge = ascending-index tie preference.
// ---------------------------------------------------------------------------
__global__ __launch_bounds__(256) void knn_kernel(const float4* __restrict__ cand,
                                                  int* __restrict__ nbr) {
    __shared__ float md[64][33];
    __shared__ int   mi[64][33];
    int tid = threadIdx.x;
    int lane = tid & 63;
    int w = __builtin_amdgcn_readfirstlane(tid >> 6);   // stripe / wave id
    int b = blockIdx.y;
    int base = blockIdx.x * 64;
    const float4* C = cand + ((size_t)b << 11);
    const float4* CS = C + (w << 9);                    // wave-uniform stripe base

    int n = base + lane;
    float4 me = C[n];
    float xi = me.x, yi = me.y, zi = me.z, qi = me.w;

    // ---- pass 1: top-8 groups (of 8 consecutive candidates) by group-min
    float gd[8]; int gi[8];
#pragma unroll
    for (int t = 0; t < 8; ++t) { gd[t] = 3.4e38f; gi[t] = 0; }
#pragma unroll 1
    for (int g = 0; g < 64; ++g) {
        float4 cv[8];
#pragma unroll
        for (int i = 0; i < 8; ++i) cv[i] = CS[g * 8 + i];   // uniform -> scalar
        float gm = 3.4e38f;
#pragma unroll
        for (int i = 0; i < 8; ++i) {
            float inner = xi * cv[i].x + yi * cv[i].y + zi * cv[i].z;
            float d = qi + cv[i].w - 2.0f * inner;
            gm = fminf(gm, d);
        }
        bool c[8];
#pragma unroll
        for (int t = 0; t < 8; ++t) c[t] = gm < gd[t];
#pragma unroll
        for (int t = 7; t >= 1; --t) {
            gd[t] = c[t - 1] ? gd[t - 1] : (c[t] ? gm : gd[t]);
            gi[t] = c[t - 1] ? gi[t - 1] : (c[t] ? g : gi[t]);
        }
        gd[0] = c[0] ? gm : gd[0];
        gi[0] = c[0] ? g : gi[0];
    }

    unsigned long long mask = 0ull;
#pragma unroll
    for (int t = 0; t < 8; ++t) mask |= (1ull << gi[t]);

    // ---- pass 2: full insert over winning groups (per-lane groups -> vector
    // global reads, 32 KB/batch is L1/L2-hot), ascending group order
    float bd[8]; int bi[8];
#pragma unroll
    for (int t = 0; t < 8; ++t) { bd[t] = 3.4e38f; bi[t] = 0; }
    while (mask) {
        int g = (int)__builtin_ctzll(mask);
        mask &= (mask - 1ull);
        int jb = (w << 9) + g * 8;
#pragma unroll
        for (int i = 0; i < 8; ++i) {
            int j = jb + i;
            float4 c4v = C[j];
            float inner = xi * c4v.x + yi * c4v.y + zi * c4v.z;
            float d = qi + c4v.w - 2.0f * inner;
            bool c[8];
#pragma unroll
            for (int t = 0; t < 8; ++t) c[t] = d < bd[t];
#pragma unroll
            for (int t = 7; t >= 1; --t) {
                bd[t] = c[t - 1] ? bd[t - 1] : (c[t] ? d : bd[t]);
                bi[t] = c[t - 1] ? bi[t - 1] : (c[t] ? j : bi[t]);
            }
            bd[0] = c[0] ? d : bd[0];
            bi[0] = c[0] ? j : bi[0];
        }
    }
#pragma unroll
    for (int t = 0; t < 8; ++t) {
        md[lane][w * 8 + t] = bd[t];
        mi[lane][w * 8 + t] = bi[t];
    }
    __syncthreads();

    if (tid < 64) {
        float fd[8]; int fi[8];
#pragma unroll
        for (int t = 0; t < 8; ++t) { fd[t] = 3.4e38f; fi[t] = 0; }
#pragma unroll 4
        for (int cc = 0; cc < 32; ++cc) {
            float d = md[tid][cc];
            int j = mi[tid][cc];
            bool c[8];
#pragma unroll
            for (int t = 0; t < 8; ++t) c[t] = d < fd[t];
#pragma unroll
            for (int t = 7; t >= 1; --t) {
                fd[t] = c[t - 1] ? fd[t - 1] : (c[t] ? d : fd[t]);
                fi[t] = c[t - 1] ? fi[t - 1] : (c[t] ? j : fi[t]);
            }
            fd[0] = c[0] ? d : fd[0];
            fi[0] = c[0] ? j : fi[0];
        }
        int row = b * NP + base + tid;
#pragma unroll
        for (int t = 0; t < 7; ++t) nbr[row * 7 + t] = fi[t + 1];
    }
}

// ---------------------------------------------------------------------------
// Generic batched transpose of last two dims: in (B,R,S) -> out (B,S,R)
// ---------------------------------------------------------------------------
__global__ __launch_bounds__(256) void transpose_kernel(const float* __restrict__ in,
                                                        float* __restrict__ out,
                                                        int R, int S) {
    __shared__ float t[32][33];
    int b = blockIdx.z;
    int s0 = blockIdx.x * 32, r0 = blockIdx.y * 32;
    const float* I = in + (size_t)b * R * S;
    float* O = out + (size_t)b * R * S;
#pragma unroll
    for (int i = 0; i < 4; ++i) {
        int r = r0 + threadIdx.y + i * 8;
        t[threadIdx.y + i * 8][threadIdx.x] = I[(size_t)r * S + s0 + threadIdx.x];
    }
    __syncthreads();
#pragma unroll
    for (int i = 0; i < 4; ++i) {
        int s = s0 + threadIdx.y + i * 8;
        O[(size_t)s * R + r0 + threadIdx.x] = t[threadIdx.x][threadIdx.y + i * 8];
    }
}

// ---------------------------------------------------------------------------
// Fused GCN block v3 (round-11, green): MFMA split-bf16, pre-split W, inline
// A split, XCD-aware swizzle (each XCD owns 2 batches -> gathers fit L2).
// ---------------------------------------------------------------------------
template <int MODE>
__global__ __launch_bounds__(512) void gemm_fused_kernel(const float* __restrict__ Asrc,
                                                         const float* __restrict__ Y2in,
                                                         const int* __restrict__ nbr,
                                                         const uint4* __restrict__ WPc,
                                                         const uint4* __restrict__ WPg,
                                                         float* __restrict__ Zout,
                                                         float* __restrict__ Y2out) {
    __shared__ unsigned short AhT[64][136];   // 17.4 KB
    __shared__ unsigned short AlT[64][136];   // 17.4 KB
    __shared__ int s_nb[448];
    int tid = threadIdx.x;
    int wid = tid >> 6, lane = tid & 63;
    int quad = lane >> 4, l15 = lane & 15;
    int xcd = blockIdx.x & 7;
    int slot = blockIdx.x >> 3;
    int bb = xcd * 2 + (slot >> 5);           // batch
    int n0 = (slot & 31) << 6;                // tile base within batch
    size_t m0 = (size_t)bb * NP + n0;
    int ncol = wid * 16 + l15;

    // ---- W frags: pre-split, frag-ordered; 16 L2-hot b128 loads, zero VALU
    BU Bch[4], Bcl[4], Bgh[4], Bgl[4];
#pragma unroll
    for (int s = 0; s < 4; ++s) {
        int idx = ((s * 4 + quad) * 128 + ncol) * 2;
        Bch[s].u = WPc[idx];
        Bcl[s].u = WPc[idx + 1];
        Bgh[s].u = WPg[idx];
        Bgl[s].u = WPg[idx + 1];
    }

    // ---- stage A tile, splitting to bf16 planes inline
    if (MODE == 1) {
        if (tid < 448) s_nb[tid] = nbr[m0 * 7 + tid];
        __syncthreads();
        size_t bbase = (size_t)bb * NP;
#pragma unroll 1
        for (int it = 0; it < 4; ++it) {
            int f = tid + it * 512;
            int r = f >> 5, c4 = (f & 31) * 4;
            size_t row = m0 + r;
            float4 z = *((const float4*)(Asrc + row * NC + c4));
            float4 acc = *((const float4*)(Y2in + row * NC + c4));
#pragma unroll
            for (int t = 0; t < 7; ++t) {
                int j = s_nb[r * 7 + t];
                float4 v = *((const float4*)(Y2in + (bbase + (size_t)j) * NC + c4));
                acc.x += v.x; acc.y += v.y; acc.z += v.z; acc.w += v.w;
            }
            float4 a;
            a.x = OMA_F * (0.125f * acc.x) + z.x;
            a.y = OMA_F * (0.125f * acc.y) + z.y;
            a.z = OMA_F * (0.125f * acc.z) + z.z;
            a.w = OMA_F * (0.125f * acc.w) + z.w;
            unsigned h01, l01, h23, l23;
            split2(a.x, a.y, h01, l01);
            split2(a.z, a.w, h23, l23);
            *((uint2*)&AhT[r][c4]) = make_uint2(h01, h23);
            *((uint2*)&AlT[r][c4]) = make_uint2(l01, l23);
        }
    } else {
        // A[r][c] = points[b][c][n0+r]: float4 along n, split scalar, b16 writes
#pragma unroll
        for (int it = 0; it < 4; ++it) {
            int f = tid + it * 512;
            int c = f >> 4, rq = (f & 15) * 4;
            float4 v = *((const float4*)(Asrc + ((size_t)bb * NC + c) * NP + n0 + rq));
            float vv[4] = {v.x, v.y, v.z, v.w};
#pragma unroll
            for (int k = 0; k < 4; ++k) {
                unsigned short h, l;
                split1(vv[k], h, l);
                AhT[rq + k][c] = h;
                AlT[rq + k][c] = l;
            }
        }
    }
    __syncthreads();

    ffrag accC[4], accG[4];
#pragma unroll
    for (int mt = 0; mt < 4; ++mt) { accC[mt] = (ffrag)0.0f; accG[mt] = (ffrag)0.0f; }

#pragma unroll
    for (int s = 0; s < 4; ++s) {
#pragma unroll
        for (int mt = 0; mt < 4; ++mt) {
            int m = mt * 16 + l15;
            int k = s * 32 + quad * 8;
            BU ah, al, rh, rl;
            ah.u = *((const uint4*)&AhT[m][k]);
            al.u = *((const uint4*)&AlT[m][k]);
#pragma unroll
            for (int w = 0; w < 4; ++w) {
                unsigned msk = ((ah.w[w] & 0x80008000u) >> 15) * 0xFFFFu;
                rh.w[w] = ah.w[w] & ~msk;
                rl.w[w] = al.w[w] & ~msk;
            }
            accC[mt] = __builtin_amdgcn_mfma_f32_16x16x32_bf16(rh.v, Bch[s].v, accC[mt], 0, 0, 0);
            accC[mt] = __builtin_amdgcn_mfma_f32_16x16x32_bf16(rh.v, Bcl[s].v, accC[mt], 0, 0, 0);
            accC[mt] = __builtin_amdgcn_mfma_f32_16x16x32_bf16(rl.v, Bch[s].v, accC[mt], 0, 0, 0);
            accG[mt] = __builtin_amdgcn_mfma_f32_16x16x32_bf16(ah.v, Bgh[s].v, accG[mt], 0, 0, 0);
            accG[mt] = __builtin_amdgcn_mfma_f32_16x16x32_bf16(ah.v, Bgl[s].v, accG[mt], 0, 0, 0);
            accG[mt] = __builtin_amdgcn_mfma_f32_16x16x32_bf16(al.v, Bgh[s].v, accG[mt], 0, 0, 0);
        }
    }

    // ---- epilogue: col = l15, row = 4*quad + r; residual p = hi + lo
#pragma unroll
    for (int mt = 0; mt < 4; ++mt) {
        int rbase = mt * 16 + quad * 4;
#pragma unroll
        for (int r = 0; r < 4; ++r) {
            int rr = rbase + r;
            unsigned hb = ((unsigned)AhT[rr][ncol]) << 16;
            unsigned lb = ((unsigned)AlT[rr][ncol]) << 16;
            float hp, lp;
            __builtin_memcpy(&hp, &hb, 4);
            __builtin_memcpy(&lp, &lb, 4);
            float p = hp + lp;
            size_t idx = (m0 + rr) * NC + ncol;
            Zout[idx] = p + ALPHA_F * accC[mt][r];
            Y2out[idx] = accG[mt][r];
        }
    }
}

// ---------------------------------------------------------------------------
// Aggregate + XCD-aware swizzle (round-11, green)
// ---------------------------------------------------------------------------
__global__ __launch_bounds__(256) void agg_kernel(const float* __restrict__ Z,
                                                  const float* __restrict__ Y2,
                                                  const int* __restrict__ nbr,
                                                  float* __restrict__ Pout) {
    int tid = threadIdx.x;
    int lane = tid & 31, rl = tid >> 5;
    int xcd = blockIdx.x & 7;
    int slot = blockIdx.x >> 3;
    int bb = xcd * 2 + (slot >> 8);
    int rblk = slot & 255;
    size_t row = ((size_t)bb << 11) + rblk * 8 + rl;
    const int* nb = nbr + row * 7;
    size_t off = row * NC + lane * 4;
    float4 ys = *((const float4*)(Y2 + off));
    size_t bbase = (size_t)bb * NP * NC;
#pragma unroll
    for (int t = 0; t < 7; ++t) {
        int j = nb[t];
        float4 v = *((const float4*)(Y2 + bbase + (size_t)j * NC + lane * 4));
        ys.x += v.x; ys.y += v.y; ys.z += v.z; ys.w += v.w;
    }
    float4 z = *((const float4*)(Z + off));
    float4 o;
    o.x = OMA_F * (0.125f * ys.x) + z.x;
    o.y = OMA_F * (0.125f * ys.y) + z.y;
    o.z = OMA_F * (0.125f * ys.z) + z.z;
    o.w = OMA_F * (0.125f * ys.w) + z.w;
    *((float4*)(Pout + off)) = o;
}

// ---------------------------------------------------------------------------
// Final small GEMMs: U1 = P @ Wuc^T (6), U2 = P @ Wug^T (6); U row = [U1|U2]
// ---------------------------------------------------------------------------
__global__ __launch_bounds__(256) void final_gemm_kernel(const float* __restrict__ P,
                                                         const float* __restrict__ Wuc,
                                                         const float* __restrict__ Wug,
                                                         float* __restrict__ U) {
    __shared__ float s1[6 * NC], s2[6 * NC];
    for (int m = threadIdx.x; m < 6 * NC; m += 256) { s1[m] = Wuc[m]; s2[m] = Wug[m]; }
    __syncthreads();
    size_t row = (size_t)blockIdx.x * 256 + threadIdx.x;
    const float4* prow = (const float4*)(P + row * NC);
    float a1[6] = {0, 0, 0, 0, 0, 0}, a2[6] = {0, 0, 0, 0, 0, 0};
#pragma unroll 4
    for (int c4 = 0; c4 < NC / 4; ++c4) {
        float4 p = prow[c4];
#pragma unroll
        for (int o = 0; o < 6; ++o) {
            float4 w1 = *((const float4*)&s1[o * NC + c4 * 4]);
            float4 w2 = *((const float4*)&s2[o * NC + c4 * 4]);
            a1[o] += p.x * w1.x + p.y * w1.y + p.z * w1.z + p.w * w1.w;
            a2[o] += p.x * w2.x + p.y * w2.y + p.z * w2.z + p.w * w2.w;
        }
    }
#pragma unroll
    for (int o = 0; o < 6; ++o) {
        U[row * 12 + o] = a1[o];
        U[row * 12 + 6 + o] = a2[o];
    }
}

// ---------------------------------------------------------------------------
// Final output: new_xyz
// ---------------------------------------------------------------------------
__global__ __launch_bounds__(256) void final_out_kernel(const float* __restrict__ U,
                                                        const int* __restrict__ nbr,
                                                        const float* __restrict__ xyz,
                                                        float* __restrict__ out) {
    size_t row = (size_t)blockIdx.x * 256 + threadIdx.x;
    int b = (int)(row >> 11), n = (int)(row & 2047);
    const int* nb = nbr + row * 7;
    float u1[6], u2[6];
#pragma unroll
    for (int o = 0; o < 6; ++o) { u1[o] = U[row * 12 + o]; u2[o] = U[row * 12 + 6 + o]; }
#pragma unroll
    for (int t = 0; t < 7; ++t) {
        int j = nb[t];
        const float* Uj = U + ((size_t)b * NP + j) * 12 + 6;
#pragma unroll
        for (int o = 0; o < 6; ++o) u2[o] += Uj[o];
    }
#pragma unroll
    for (int c = 0; c < 3; ++c)
#pragma unroll
        for (int s = 0; s < 2; ++s) {
            int o = c * 2 + s;
            float val = ALPHA_F * u1[o] + OMA_F * (0.125f * u2[o])
                      + xyz[(size_t)b * 3 * NP + (size_t)c * NP + n];
            out[(size_t)b * 3 * 2 * NP + (size_t)c * 2 * NP + (size_t)s * NP + n] = val;
        }
}

// ---------------------------------------------------------------------------
extern "C" void kernel_launch(void* const* d_in, const int* in_sizes, int n_in,
                              void* d_out, int out_size, void* d_ws, size_t ws_size,
                              hipStream_t stream) {
    const float* xyz    = (const float*)d_in[0];  // (16,3,2048)
    const float* points = (const float*)d_in[1];  // (16,128,2048)
    const float* Wc     = (const float*)d_in[2];  // (4,128,128)
    const float* Wg     = (const float*)d_in[3];  // (4,128,128)
    const float* Wuc    = (const float*)d_in[4];  // (6,128)
    const float* Wug    = (const float*)d_in[5];  // (6,128)
    float* out = (float*)d_out;

    char* ws = (char*)d_ws;
    size_t o = 0;
    int* nbr    = (int*)(ws + o);    o += (size_t)NB * NP * 7 * 4;
    uint4* WP   = (uint4*)(ws + o);  o += (size_t)32768 * 16;          // 0.5 MB
    float4* CAND = (float4*)(ws + o); o += (size_t)NB * NP * 16;       // 0.5 MB
    float* Za = (float*)(ws + o);    o += (size_t)NB * NP * NC * 4;    // 16 MB
    float* Ya = (float*)(ws + o);    o += (size_t)NB * NP * NC * 4;
    float* Zb = (float*)(ws + o);    o += (size_t)NB * NP * NC * 4;
    float* Yb = (float*)(ws + o);    o += (size_t)NB * NP * NC * 4;
    float* U  = (float*)(ws + o);    o += (size_t)NB * NP * 12 * 4;

    const int GEMM_GRID = NB * NP / 64;   // 512 tiles
    // WP slab bases: (layer*2 + mat) * 4096 uint4
    #define WPC(L) (WP + (size_t)((L) * 2 + 0) * 4096)
    #define WPG(L) (WP + (size_t)((L) * 2 + 1) * 4096)

    // 0) one-time prep: W split (blocks 0..63) + candidate packing (64..191)
    prep_kernel<<<192, 256, 0, stream>>>(Wc, Wg, xyz, WP, CAND);
    // 1) KNN (consumes CAND)
    knn_kernel<<<dim3(NP / 64, NB), 256, 0, stream>>>(CAND, nbr);
    // 2) GCN blocks — agg fused into next block's A-staging
    gemm_fused_kernel<0><<<GEMM_GRID, 512, 0, stream>>>(points, nullptr, nullptr,
        WPC(0), WPG(0), Za, Ya);
    gemm_fused_kernel<1><<<GEMM_GRID, 512, 0, stream>>>(Za, Ya, nbr,
        WPC(1), WPG(1), Zb, Yb);
    gemm_fused_kernel<1><<<GEMM_GRID, 512, 0, stream>>>(Zb, Yb, nbr,
        WPC(2), WPG(2), Za, Ya);
    gemm_fused_kernel<1><<<GEMM_GRID, 512, 0, stream>>>(Za, Ya, nbr,
        WPC(3), WPG(3), Zb, Yb);
    // 3) last agg -> P5 (reuse Za)
    float* P5 = Za;
    agg_kernel<<<dim3(NB * NP / 8), 256, 0, stream>>>(Zb, Yb, nbr, P5);
    // 4) final small GEMMs
    final_gemm_kernel<<<dim3(NB * NP / 256), 256, 0, stream>>>(P5, Wuc, Wug, U);
    // 5) new_xyz
    final_out_kernel<<<dim3(NB * NP / 256), 256, 0, stream>>>(U, nbr, xyz, out);
    // 6) pts (B,N,C) -> out2 (B,C,N)
    transpose_kernel<<<dim3(NC / 32, NP / 32, NB), dim3(32, 8), 0, stream>>>(
        P5, out + (size_t)NB * 3 * 2 * NP, NP, NC);
}

// Round 14
// 227.235 us; speedup vs baseline: 1.0468x; 1.0468x over previous
//
#include <hip/hip_runtime.h>
#include <hip/hip_bf16.h>

// Problem constants
static constexpr int NB = 16;     // batches
static constexpr int NP = 2048;   // points per batch
static constexpr int NC = 128;    // channels
#define ALPHA_F ((float)(8.0/9.0))
#define OMA_F   ((float)(1.0 - 8.0/9.0))

typedef __attribute__((ext_vector_type(8))) short bfrag;   // 8 bf16 (4 VGPR)
typedef __attribute__((ext_vector_type(4))) float ffrag;   // 4 fp32 acc

union BU { bfrag v; uint4 u; unsigned int w[4]; };

// split two floats into packed bf16 hi pair + bf16 lo pair
__device__ inline void split2(float x, float y, unsigned& hi, unsigned& lo) {
    __hip_bfloat162 h = __float22bfloat162_rn(make_float2(x, y));
    float2 hb = __bfloat1622float2(h);
    __hip_bfloat162 l = __float22bfloat162_rn(make_float2(x - hb.x, y - hb.y));
    __builtin_memcpy(&hi, &h, 4);
    __builtin_memcpy(&lo, &l, 4);
}

__device__ inline void split1(float x, unsigned short& h, unsigned short& l) {
    __hip_bfloat16 hb = __float2bfloat16(x);
    float hf = __bfloat162float(hb);
    __hip_bfloat16 lb = __float2bfloat16(x - hf);
    __builtin_memcpy(&h, &hb, 2);
    __builtin_memcpy(&l, &lb, 2);
}

// ---------------------------------------------------------------------------
// KNN v4c (round-11 semantics, green, absmax 0.03125): grouped two-phase scan.
// Pass-1 group loop unroll 2: doubles in-flight ds_read_b128 (VALUBusy was 63%).
// ---------------------------------------------------------------------------
__global__ __launch_bounds__(256) void knn_kernel(const float* __restrict__ xyz,
                                                  int* __restrict__ nbr) {
    __shared__ float4 sp[NP];            // 32 KB
    __shared__ float  md[64][33];
    __shared__ int    mi[64][33];
    int b = blockIdx.y;
    const float* X = xyz + (size_t)b * 3 * NP;
    for (int m = threadIdx.x; m < NP; m += 256) {
        float x = X[m], y = X[NP + m], z = X[2 * NP + m];
        sp[m] = make_float4(x, y, z, x * x + y * y + z * z);
    }
    __syncthreads();

    int tid = threadIdx.x;
    int p = tid >> 2;
    int q = tid & 3;
    int base = blockIdx.x * 64;
    int n = base + p;
    float4 me = sp[n];
    float xi = me.x, yi = me.y, zi = me.z, qi = me.w;

    // ---- pass 1: top-8 groups by group-min
    float gd[8]; int gi[8];
#pragma unroll
    for (int t = 0; t < 8; ++t) { gd[t] = 3.4e38f; gi[t] = 0; }
#pragma unroll 2
    for (int g = 0; g < 64; ++g) {
        float gm = 3.4e38f;
#pragma unroll
        for (int i = 0; i < 8; ++i) {
            int j = (g * 8 + i) * 4 + q;
            float4 c4v = sp[j];
            float inner = xi * c4v.x + yi * c4v.y + zi * c4v.z;
            float d = qi + c4v.w - 2.0f * inner;
            gm = fminf(gm, d);
        }
        bool c[8];
#pragma unroll
        for (int t = 0; t < 8; ++t) c[t] = gm < gd[t];
#pragma unroll
        for (int t = 7; t >= 1; --t) {
            gd[t] = c[t - 1] ? gd[t - 1] : (c[t] ? gm : gd[t]);
            gi[t] = c[t - 1] ? gi[t - 1] : (c[t] ? g : gi[t]);
        }
        gd[0] = c[0] ? gm : gd[0];
        gi[0] = c[0] ? g : gi[0];
    }

    unsigned long long mask = 0ull;
#pragma unroll
    for (int t = 0; t < 8; ++t) mask |= (1ull << gi[t]);

    // ---- pass 2: full insert over winning groups, ascending group order
    float bd[8]; int bi[8];
#pragma unroll
    for (int t = 0; t < 8; ++t) { bd[t] = 3.4e38f; bi[t] = 0; }
    while (mask) {
        int g = (int)__builtin_ctzll(mask);
        mask &= (mask - 1ull);
#pragma unroll
        for (int i = 0; i < 8; ++i) {
            int j = (g * 8 + i) * 4 + q;
            float4 c4v = sp[j];
            float inner = xi * c4v.x + yi * c4v.y + zi * c4v.z;
            float d = qi + c4v.w - 2.0f * inner;
            bool c[8];
#pragma unroll
            for (int t = 0; t < 8; ++t) c[t] = d < bd[t];
#pragma unroll
            for (int t = 7; t >= 1; --t) {
                bd[t] = c[t - 1] ? bd[t - 1] : (c[t] ? d : bd[t]);
                bi[t] = c[t - 1] ? bi[t - 1] : (c[t] ? j : bi[t]);
            }
            bd[0] = c[0] ? d : bd[0];
            bi[0] = c[0] ? j : bi[0];
        }
    }
#pragma unroll
    for (int t = 0; t < 8; ++t) {
        md[p][q * 8 + t] = bd[t];
        mi[p][q * 8 + t] = bi[t];
    }
    __syncthreads();

    if (tid < 64) {
        float fd[8]; int fi[8];
#pragma unroll
        for (int t = 0; t < 8; ++t) { fd[t] = 3.4e38f; fi[t] = 0; }
#pragma unroll 4
        for (int cc = 0; cc < 32; ++cc) {
            float d = md[tid][cc];
            int j = mi[tid][cc];
            bool c[8];
#pragma unroll
            for (int t = 0; t < 8; ++t) c[t] = d < fd[t];
#pragma unroll
            for (int t = 7; t >= 1; --t) {
                fd[t] = c[t - 1] ? fd[t - 1] : (c[t] ? d : fd[t]);
                fi[t] = c[t - 1] ? fi[t - 1] : (c[t] ? j : fi[t]);
            }
            fd[0] = c[0] ? d : fd[0];
            fi[0] = c[0] ? j : fi[0];
        }
        int row = b * NP + base + tid;
#pragma unroll
        for (int t = 0; t < 7; ++t) nbr[row * 7 + t] = fi[t + 1];
    }
}

// ---------------------------------------------------------------------------
// Generic batched transpose of last two dims: in (B,R,S) -> out (B,S,R)
// ---------------------------------------------------------------------------
__global__ __launch_bounds__(256) void transpose_kernel(const float* __restrict__ in,
                                                        float* __restrict__ out,
                                                        int R, int S) {
    __shared__ float t[32][33];
    int b = blockIdx.z;
    int s0 = blockIdx.x * 32, r0 = blockIdx.y * 32;
    const float* I = in + (size_t)b * R * S;
    float* O = out + (size_t)b * R * S;
#pragma unroll
    for (int i = 0; i < 4; ++i) {
        int r = r0 + threadIdx.y + i * 8;
        t[threadIdx.y + i * 8][threadIdx.x] = I[(size_t)r * S + s0 + threadIdx.x];
    }
    __syncthreads();
#pragma unroll
    for (int i = 0; i < 4; ++i) {
        int s = s0 + threadIdx.y + i * 8;
        O[(size_t)s * R + r0 + threadIdx.x] = t[threadIdx.x][threadIdx.y + i * 8];
    }
}

// ---------------------------------------------------------------------------
// Pre-split W into MFMA-frag-ordered bf16 hi/lo uint4 pairs (one-time).
// ---------------------------------------------------------------------------
__global__ __launch_bounds__(256) void prep_w_kernel(const float* __restrict__ Wc,
                                                     const float* __restrict__ Wg,
                                                     uint4* __restrict__ WP) {
    int t = blockIdx.x * 256 + threadIdx.x;
    int ncol = t & 127;
    int quad = (t >> 7) & 3;
    int s = (t >> 9) & 3;
    int mat = (t >> 11) & 1;
    int layer = t >> 12;
    const float* W = (mat ? Wg : Wc) + (size_t)layer * NC * NC + (size_t)ncol * NC + s * 32 + quad * 8;
    float4 a = *((const float4*)W);
    float4 b = *((const float4*)(W + 4));
    BU hi, lo;
    split2(a.x, a.y, hi.w[0], lo.w[0]);
    split2(a.z, a.w, hi.w[1], lo.w[1]);
    split2(b.x, b.y, hi.w[2], lo.w[2]);
    split2(b.z, b.w, hi.w[3], lo.w[3]);
    WP[t * 2] = hi.u;
    WP[t * 2 + 1] = lo.u;
}

// ---------------------------------------------------------------------------
// Fused GCN block v3 (round-11, green): MFMA split-bf16, pre-split W, inline
// A split, XCD-aware swizzle (each XCD owns 2 batches -> gathers fit L2).
// MODE-1 staging loop unroll 2: doubles in-flight gather loads (latency-bound).
// ---------------------------------------------------------------------------
template <int MODE>
__global__ __launch_bounds__(512) void gemm_fused_kernel(const float* __restrict__ Asrc,
                                                         const float* __restrict__ Y2in,
                                                         const int* __restrict__ nbr,
                                                         const uint4* __restrict__ WPc,
                                                         const uint4* __restrict__ WPg,
                                                         float* __restrict__ Zout,
                                                         float* __restrict__ Y2out) {
    __shared__ unsigned short AhT[64][136];   // 17.4 KB
    __shared__ unsigned short AlT[64][136];   // 17.4 KB
    __shared__ int s_nb[448];
    int tid = threadIdx.x;
    int wid = tid >> 6, lane = tid & 63;
    int quad = lane >> 4, l15 = lane & 15;
    int xcd = blockIdx.x & 7;
    int slot = blockIdx.x >> 3;
    int bb = xcd * 2 + (slot >> 5);           // batch
    int n0 = (slot & 31) << 6;                // tile base within batch
    size_t m0 = (size_t)bb * NP + n0;
    int ncol = wid * 16 + l15;

    // ---- W frags: pre-split, frag-ordered; 16 L2-hot b128 loads, zero VALU
    BU Bch[4], Bcl[4], Bgh[4], Bgl[4];
#pragma unroll
    for (int s = 0; s < 4; ++s) {
        int idx = ((s * 4 + quad) * 128 + ncol) * 2;
        Bch[s].u = WPc[idx];
        Bcl[s].u = WPc[idx + 1];
        Bgh[s].u = WPg[idx];
        Bgl[s].u = WPg[idx + 1];
    }

    // ---- stage A tile, splitting to bf16 planes inline
    if (MODE == 1) {
        if (tid < 448) s_nb[tid] = nbr[m0 * 7 + tid];
        __syncthreads();
        size_t bbase = (size_t)bb * NP;
#pragma unroll 2
        for (int it = 0; it < 4; ++it) {
            int f = tid + it * 512;
            int r = f >> 5, c4 = (f & 31) * 4;
            size_t row = m0 + r;
            float4 z = *((const float4*)(Asrc + row * NC + c4));
            float4 acc = *((const float4*)(Y2in + row * NC + c4));
#pragma unroll
            for (int t = 0; t < 7; ++t) {
                int j = s_nb[r * 7 + t];
                float4 v = *((const float4*)(Y2in + (bbase + (size_t)j) * NC + c4));
                acc.x += v.x; acc.y += v.y; acc.z += v.z; acc.w += v.w;
            }
            float4 a;
            a.x = OMA_F * (0.125f * acc.x) + z.x;
            a.y = OMA_F * (0.125f * acc.y) + z.y;
            a.z = OMA_F * (0.125f * acc.z) + z.z;
            a.w = OMA_F * (0.125f * acc.w) + z.w;
            unsigned h01, l01, h23, l23;
            split2(a.x, a.y, h01, l01);
            split2(a.z, a.w, h23, l23);
            *((uint2*)&AhT[r][c4]) = make_uint2(h01, h23);
            *((uint2*)&AlT[r][c4]) = make_uint2(l01, l23);
        }
    } else {
        // A[r][c] = points[b][c][n0+r]: float4 along n, split scalar, b16 writes
#pragma unroll
        for (int it = 0; it < 4; ++it) {
            int f = tid + it * 512;
            int c = f >> 4, rq = (f & 15) * 4;
            float4 v = *((const float4*)(Asrc + ((size_t)bb * NC + c) * NP + n0 + rq));
            float vv[4] = {v.x, v.y, v.z, v.w};
#pragma unroll
            for (int k = 0; k < 4; ++k) {
                unsigned short h, l;
                split1(vv[k], h, l);
                AhT[rq + k][c] = h;
                AlT[rq + k][c] = l;
            }
        }
    }
    __syncthreads();

    ffrag accC[4], accG[4];
#pragma unroll
    for (int mt = 0; mt < 4; ++mt) { accC[mt] = (ffrag)0.0f; accG[mt] = (ffrag)0.0f; }

#pragma unroll
    for (int s = 0; s < 4; ++s) {
#pragma unroll
        for (int mt = 0; mt < 4; ++mt) {
            int m = mt * 16 + l15;
            int k = s * 32 + quad * 8;
            BU ah, al, rh, rl;
            ah.u = *((const uint4*)&AhT[m][k]);
            al.u = *((const uint4*)&AlT[m][k]);
#pragma unroll
            for (int w = 0; w < 4; ++w) {
                unsigned msk = ((ah.w[w] & 0x80008000u) >> 15) * 0xFFFFu;
                rh.w[w] = ah.w[w] & ~msk;
                rl.w[w] = al.w[w] & ~msk;
            }
            accC[mt] = __builtin_amdgcn_mfma_f32_16x16x32_bf16(rh.v, Bch[s].v, accC[mt], 0, 0, 0);
            accC[mt] = __builtin_amdgcn_mfma_f32_16x16x32_bf16(rh.v, Bcl[s].v, accC[mt], 0, 0, 0);
            accC[mt] = __builtin_amdgcn_mfma_f32_16x16x32_bf16(rl.v, Bch[s].v, accC[mt], 0, 0, 0);
            accG[mt] = __builtin_amdgcn_mfma_f32_16x16x32_bf16(ah.v, Bgh[s].v, accG[mt], 0, 0, 0);
            accG[mt] = __builtin_amdgcn_mfma_f32_16x16x32_bf16(ah.v, Bgl[s].v, accG[mt], 0, 0, 0);
            accG[mt] = __builtin_amdgcn_mfma_f32_16x16x32_bf16(al.v, Bgh[s].v, accG[mt], 0, 0, 0);
        }
    }

    // ---- epilogue: col = l15, row = 4*quad + r; residual p = hi + lo
#pragma unroll
    for (int mt = 0; mt < 4; ++mt) {
        int rbase = mt * 16 + quad * 4;
#pragma unroll
        for (int r = 0; r < 4; ++r) {
            int rr = rbase + r;
            unsigned hb = ((unsigned)AhT[rr][ncol]) << 16;
            unsigned lb = ((unsigned)AlT[rr][ncol]) << 16;
            float hp, lp;
            __builtin_memcpy(&hp, &hb, 4);
            __builtin_memcpy(&lp, &lb, 4);
            float p = hp + lp;
            size_t idx = (m0 + rr) * NC + ncol;
            Zout[idx] = p + ALPHA_F * accC[mt][r];
            Y2out[idx] = accG[mt][r];
        }
    }
}

// ---------------------------------------------------------------------------
// Aggregate + XCD-aware swizzle (round-11, green)
// ---------------------------------------------------------------------------
__global__ __launch_bounds__(256) void agg_kernel(const float* __restrict__ Z,
                                                  const float* __restrict__ Y2,
                                                  const int* __restrict__ nbr,
                                                  float* __restrict__ Pout) {
    int tid = threadIdx.x;
    int lane = tid & 31, rl = tid >> 5;
    int xcd = blockIdx.x & 7;
    int slot = blockIdx.x >> 3;
    int bb = xcd * 2 + (slot >> 8);
    int rblk = slot & 255;
    size_t row = ((size_t)bb << 11) + rblk * 8 + rl;
    const int* nb = nbr + row * 7;
    size_t off = row * NC + lane * 4;
    float4 ys = *((const float4*)(Y2 + off));
    size_t bbase = (size_t)bb * NP * NC;
#pragma unroll
    for (int t = 0; t < 7; ++t) {
        int j = nb[t];
        float4 v = *((const float4*)(Y2 + bbase + (size_t)j * NC + lane * 4));
        ys.x += v.x; ys.y += v.y; ys.z += v.z; ys.w += v.w;
    }
    float4 z = *((const float4*)(Z + off));
    float4 o;
    o.x = OMA_F * (0.125f * ys.x) + z.x;
    o.y = OMA_F * (0.125f * ys.y) + z.y;
    o.z = OMA_F * (0.125f * ys.z) + z.z;
    o.w = OMA_F * (0.125f * ys.w) + z.w;
    *((float4*)(Pout + off)) = o;
}

// ---------------------------------------------------------------------------
// Final small GEMMs: U1 = P @ Wuc^T (6), U2 = P @ Wug^T (6); U row = [U1|U2]
// ---------------------------------------------------------------------------
__global__ __launch_bounds__(256) void final_gemm_kernel(const float* __restrict__ P,
                                                         const float* __restrict__ Wuc,
                                                         const float* __restrict__ Wug,
                                                         float* __restrict__ U) {
    __shared__ float s1[6 * NC], s2[6 * NC];
    for (int m = threadIdx.x; m < 6 * NC; m += 256) { s1[m] = Wuc[m]; s2[m] = Wug[m]; }
    __syncthreads();
    size_t row = (size_t)blockIdx.x * 256 + threadIdx.x;
    const float4* prow = (const float4*)(P + row * NC);
    float a1[6] = {0, 0, 0, 0, 0, 0}, a2[6] = {0, 0, 0, 0, 0, 0};
#pragma unroll 4
    for (int c4 = 0; c4 < NC / 4; ++c4) {
        float4 p = prow[c4];
#pragma unroll
        for (int o = 0; o < 6; ++o) {
            float4 w1 = *((const float4*)&s1[o * NC + c4 * 4]);
            float4 w2 = *((const float4*)&s2[o * NC + c4 * 4]);
            a1[o] += p.x * w1.x + p.y * w1.y + p.z * w1.z + p.w * w1.w;
            a2[o] += p.x * w2.x + p.y * w2.y + p.z * w2.z + p.w * w2.w;
        }
    }
#pragma unroll
    for (int o = 0; o < 6; ++o) {
        U[row * 12 + o] = a1[o];
        U[row * 12 + 6 + o] = a2[o];
    }
}

// ---------------------------------------------------------------------------
// Final output: new_xyz
// ---------------------------------------------------------------------------
__global__ __launch_bounds__(256) void final_out_kernel(const float* __restrict__ U,
                                                        const int* __restrict__ nbr,
                                                        const float* __restrict__ xyz,
                                                        float* __restrict__ out) {
    size_t row = (size_t)blockIdx.x * 256 + threadIdx.x;
    int b = (int)(row >> 11), n = (int)(row & 2047);
    const int* nb = nbr + row * 7;
    float u1[6], u2[6];
#pragma unroll
    for (int o = 0; o < 6; ++o) { u1[o] = U[row * 12 + o]; u2[o] = U[row * 12 + 6 + o]; }
#pragma unroll
    for (int t = 0; t < 7; ++t) {
        int j = nb[t];
        const float* Uj = U + ((size_t)b * NP + j) * 12 + 6;
#pragma unroll
        for (int o = 0; o < 6; ++o) u2[o] += Uj[o];
    }
#pragma unroll
    for (int c = 0; c < 3; ++c)
#pragma unroll
        for (int s = 0; s < 2; ++s) {
            int o = c * 2 + s;
            float val = ALPHA_F * u1[o] + OMA_F * (0.125f * u2[o])
                      + xyz[(size_t)b * 3 * NP + (size_t)c * NP + n];
            out[(size_t)b * 3 * 2 * NP + (size_t)c * 2 * NP + (size_t)s * NP + n] = val;
        }
}

// ---------------------------------------------------------------------------
extern "C" void kernel_launch(void* const* d_in, const int* in_sizes, int n_in,
                              void* d_out, int out_size, void* d_ws, size_t ws_size,
                              hipStream_t stream) {
    const float* xyz    = (const float*)d_in[0];  // (16,3,2048)
    const float* points = (const float*)d_in[1];  // (16,128,2048)
    const float* Wc     = (const float*)d_in[2];  // (4,128,128)
    const float* Wg     = (const float*)d_in[3];  // (4,128,128)
    const float* Wuc    = (const float*)d_in[4];  // (6,128)
    const float* Wug    = (const float*)d_in[5];  // (6,128)
    float* out = (float*)d_out;

    char* ws = (char*)d_ws;
    size_t o = 0;
    int* nbr  = (int*)(ws + o);     o += (size_t)NB * NP * 7 * 4;
    uint4* WP = (uint4*)(ws + o);   o += (size_t)32768 * 16;           // 0.5 MB
    float* Za = (float*)(ws + o);   o += (size_t)NB * NP * NC * 4;     // 16 MB
    float* Ya = (float*)(ws + o);   o += (size_t)NB * NP * NC * 4;
    float* Zb = (float*)(ws + o);   o += (size_t)NB * NP * NC * 4;
    float* Yb = (float*)(ws + o);   o += (size_t)NB * NP * NC * 4;
    float* U  = (float*)(ws + o);   o += (size_t)NB * NP * 12 * 4;

    const int GEMM_GRID = NB * NP / 64;   // 512 tiles
    // WP slab bases: (layer*2 + mat) * 4096 uint4
    #define WPC(L) (WP + (size_t)((L) * 2 + 0) * 4096)
    #define WPG(L) (WP + (size_t)((L) * 2 + 1) * 4096)

    // 0) pre-split weights (one-time)
    prep_w_kernel<<<64, 256, 0, stream>>>(Wc, Wg, WP);
    // 1) KNN
    knn_kernel<<<dim3(NP / 64, NB), 256, 0, stream>>>(xyz, nbr);
    // 2) GCN blocks — agg fused into next block's A-staging
    gemm_fused_kernel<0><<<GEMM_GRID, 512, 0, stream>>>(points, nullptr, nullptr,
        WPC(0), WPG(0), Za, Ya);
    gemm_fused_kernel<1><<<GEMM_GRID, 512, 0, stream>>>(Za, Ya, nbr,
        WPC(1), WPG(1), Zb, Yb);
    gemm_fused_kernel<1><<<GEMM_GRID, 512, 0, stream>>>(Zb, Yb, nbr,
        WPC(2), WPG(2), Za, Ya);
    gemm_fused_kernel<1><<<GEMM_GRID, 512, 0, stream>>>(Za, Ya, nbr,
        WPC(3), WPG(3), Zb, Yb);
    // 3) last agg -> P5 (reuse Za)
    float* P5 = Za;
    agg_kernel<<<dim3(NB * NP / 8), 256, 0, stream>>>(Zb, Yb, nbr, P5);
    // 4) final small GEMMs
    final_gemm_kernel<<<dim3(NB * NP / 256), 256, 0, stream>>>(P5, Wuc, Wug, U);
    // 5) new_xyz
    final_out_kernel<<<dim3(NB * NP / 256), 256, 0, stream>>>(U, nbr, xyz, out);
    // 6) pts (B,N,C) -> out2 (B,C,N)
    transpose_kernel<<<dim3(NC / 32, NP / 32, NB), dim3(32, 8), 0, stream>>>(
        P5, out + (size_t)NB * 3 * 2 * NP, NP, NC);
}